// Round 12
// baseline (362.532 us; speedup 1.0000x reference)
//
#include <hip/hip_runtime.h>
#include <hip/hip_bf16.h>
#include <math.h>

#define N_NODES 50000
#define N_EDGES 800000
#define DIM 128
#define CLS 32
#define NGRAPH 64
#define LN_EPS 1e-5f
// padded CSR capacity: sum ceil(deg/8)*8 <= E + 7*N
#define CSR_CAP (N_EDGES + 8 * N_NODES)
#define NBLK 196                         // dst-buckets of 256 nodes
#define ABLK 128                         // phase-A blocks
#define EPB (N_EDGES / ABLK)             // 6250 edges per phase-A block
#define EB_STRIDE 7168                   // per-bucket ebuf capacity
#define LCAP 8192                        // per-bucket LDS csr capacity
#define PSPLIT 16                        // pool partial splits per graph
#define ROWS1 (N_NODES + 1)              // 50001 (incl zero pad row)

typedef __attribute__((ext_vector_type(8))) short bf16x8;
typedef __attribute__((ext_vector_type(4))) float f32x4;

static __device__ __forceinline__ int lower_bound_i(const int* a, int n, int key) {
    int lo = 0, hi = n;
    while (lo < hi) { int mid = (lo + hi) >> 1; if (a[mid] < key) lo = mid + 1; else hi = mid; }
    return lo;
}

// ---- fused prep: row-major bf16 convert + weight transpose + zero scratch --

__global__ __launch_bounds__(256) void prep_kernel(
    const float* __restrict__ x, const float* __restrict__ Wself,
    const float* __restrict__ Wmsg, __hip_bfloat16* __restrict__ XbIn,
    __hip_bfloat16* __restrict__ WT,
    int* __restrict__ ecur, float* __restrict__ gsum,
    __hip_bfloat16* __restrict__ padA, __hip_bfloat16* __restrict__ padB,
    __hip_bfloat16* __restrict__ padC) {
    int i = blockIdx.x * 256 + threadIdx.x;  // grid covers N_NODES*DIM/2 = 3.2M
    if (i < N_NODES * DIM / 2) {
        float2 v = ((const float2*)x)[i];
        ((__hip_bfloat162*)XbIn)[i] = __float22bfloat162_rn(v);
    }
    if (i < 3 * 128 * 256) {
        int l = i / (128 * 256);
        int rem = i - l * (128 * 256);
        int n = rem >> 8;
        int k = rem & 255;
        float v = (k < 128) ? Wself[l * 16384 + k * 128 + n]
                            : Wmsg[l * 16384 + (k - 128) * 128 + n];
        WT[i] = __float2bfloat16(v);
    }
    if (i < NBLK) ecur[i] = i * EB_STRIDE;
    if (i < NGRAPH * DIM) gsum[i] = 0.f;
    if (i < DIM) {  // zero pad row (n = N_NODES) of the bf16 node buffers
        padA[i] = __float2bfloat16(0.f);
        padB[i] = __float2bfloat16(0.f);
        padC[i] = __float2bfloat16(0.f);
    }
}

// ---- phase A: bucket edges by dst>>8, line-exclusive reservations ----------

__global__ __launch_bounds__(1024) void bucket_kernel(
    const int* __restrict__ esrc, const int* __restrict__ edst,
    int* __restrict__ ecur, int* __restrict__ ebuf) {
    __shared__ int bc[NBLK], bres[NBLK], bcnt[NBLK];
    const int t = threadIdx.x;
    const int e0 = blockIdx.x * EPB;
    if (t < NBLK) bc[t] = 0;
    __syncthreads();
    for (int i = t; i < EPB; i += 1024)
        atomicAdd(&bc[edst[e0 + i] >> 8], 1);
    __syncthreads();
    if (t < NBLK) {
        int c = bc[t];
        int r = (c + 15) & ~15;                 // whole 64B lines
        int res = atomicAdd(&ecur[t], r);       // one global atomic per (block,bucket)
        bres[t] = res;
        bcnt[t] = c;
        bc[t] = res;
    }
    __syncthreads();
    for (int i = t; i < EPB; i += 1024) {
        int d = edst[e0 + i];
        int s = esrc[e0 + i];
        int pos = atomicAdd(&bc[d >> 8], 1);
        ebuf[pos] = ((d & 255) << 16) | s;      // src < 50000 < 2^16
    }
    __syncthreads();
    if (t < NBLK) {
        int c = bcnt[t], r = (c + 15) & ~15, base = bres[t];
        for (int j = c; j < r; j++) ebuf[base + j] = -1;  // sentinels
    }
}

// ---- phase B1: per-bucket node histogram from ebuf -------------------------

__global__ __launch_bounds__(1024) void bhist_kernel(
    const int* __restrict__ ebuf, const int* __restrict__ ecur,
    int* __restrict__ counts, int* __restrict__ btot) {
    __shared__ int ncnt[256];
    __shared__ int red[256];
    const int b = blockIdx.x, t = threadIdx.x;
    const int used = ecur[b] - b * EB_STRIDE;
    const int* eb = ebuf + b * EB_STRIDE;
    if (t < 256) ncnt[t] = 0;
    __syncthreads();
    for (int i = t; i < used; i += 1024) {
        int p = eb[i];
        if (p != -1) atomicAdd(&ncnt[p >> 16], 1);
    }
    __syncthreads();
    if (t < 256) {
        int gi = b * 256 + t;
        if (gi < N_NODES) counts[gi] = ncnt[t];
        red[t] = (ncnt[t] + 7) & ~7;
    }
    __syncthreads();
    for (int o = 128; o > 0; o >>= 1) {
        if (t < o) red[t] += red[t + o];
        __syncthreads();
    }
    if (t == 0) btot[b] = red[0];
}

// ---- phase B2: exclusive scan of 196 padded bucket totals ------------------

__global__ __launch_bounds__(256) void btot_scan_kernel(const int* __restrict__ btot,
                                                        int* __restrict__ bbase,
                                                        int* __restrict__ off) {
    __shared__ int sd[256];
    int i = threadIdx.x;
    int v = (i < NBLK) ? btot[i] : 0;
    sd[i] = v;
    __syncthreads();
    for (int o = 1; o < 256; o <<= 1) {
        int tv = (i >= o) ? sd[i - o] : 0;
        __syncthreads();
        sd[i] += tv;
        __syncthreads();
    }
    if (i < NBLK) bbase[i] = sd[i] - v;  // exclusive
    if (i == 255) off[N_NODES] = sd[255];
}

// ---- phase B3: per-bucket CSR build in LDS; writes off[] + coalesced csr ---

__global__ __launch_bounds__(1024) void csr_build_kernel(
    const int* __restrict__ ebuf, const int* __restrict__ ecur,
    const int* __restrict__ counts, const int* __restrict__ bbase,
    int* __restrict__ off, int* __restrict__ csr) {
    __shared__ int cur[256];
    __shared__ int ssc[256];
    __shared__ int lcsr[LCAP];
    const int b = blockIdx.x, t = threadIdx.x;
    const int used = ecur[b] - b * EB_STRIDE;
    const int* eb = ebuf + b * EB_STRIDE;
    const int gbase = bbase[b];
    for (int i = t; i < LCAP; i += 1024) lcsr[i] = N_NODES;  // pads -> zero row
    int myc = 0, mypad = 0;
    const int gi = b * 256 + t;
    if (t < 256) {
        myc = (gi < N_NODES) ? counts[gi] : 0;
        mypad = (myc + 7) & ~7;
        ssc[t] = mypad;
    }
    __syncthreads();
    for (int o = 1; o < 256; o <<= 1) {
        int v = 0;
        if (t < 256 && t >= o) v = ssc[t - o];
        __syncthreads();
        if (t < 256) ssc[t] += v;
        __syncthreads();
    }
    if (t < 256) {
        int eoff = ssc[t] - mypad;
        cur[t] = eoff;
        if (gi < N_NODES) off[gi] = gbase + eoff;
    }
    __syncthreads();
    for (int i = t; i < used; i += 1024) {
        int p = eb[i];
        if (p != -1) {
            int pos = atomicAdd(&cur[p >> 16], 1);
            lcsr[pos] = p & 0xFFFF;
        }
    }
    __syncthreads();
    const int total = ssc[255];
    int4* dst4 = (int4*)(csr + gbase);
    const int4* src4 = (const int4*)lcsr;
    for (int i = t; i < (total >> 2); i += 1024) dst4[i] = src4[i];
}

// ---- Fused layer: gather S-tile into LDS, then MFMA GEMM + epilogue --------
// Block = 64 rows. Phase G: each wave aggregates 16 nodes (row-major gather,
// 16 loads in flight) into LDS S-tile. Then H = [Xb|S] @ WT^T with phase-0 A
// from global Xb, phase-1 A from the S-tile. Epilogue: bias+deg*bmsg, ReLU, LN.

__global__ __launch_bounds__(256) void layer_fused_kernel(
    const __hip_bfloat16* __restrict__ Xb,
    const int* __restrict__ off, const int* __restrict__ csr,
    const __hip_bfloat16* __restrict__ WT,  // [128 n][256 k] bf16 for this layer
    const float* __restrict__ bself, const float* __restrict__ bmsg,
    const int* __restrict__ deg,
    const float* __restrict__ lng, const float* __restrict__ lnb,
    __hip_bfloat16* __restrict__ XoutB, int do_ln) {
    __shared__ __hip_bfloat16 wlds[128 * 136];  // weights (stride 136: free 2-way alias)
    __shared__ __hip_bfloat16 slds[64 * 136];   // S-tile
    const int tid = threadIdx.x;
    const int w = tid >> 6, lane = tid & 63;
    const int l15 = lane & 15, q = lane >> 4;
    const int row0 = blockIdx.x * 64;

    // --- phase G: gather 16 nodes per wave into S-tile ---
    for (int t = 0; t < 16; t++) {
        int r = w * 16 + t;
        int n = row0 + r;
        int b = 0, e = 0;
        if (n < N_NODES) { b = off[n]; e = off[n + 1]; }
        float ax = 0.f, ay = 0.f;
        int base = b;
        for (; base + 16 <= e; base += 16) {
            int idx16 = csr[base + (lane & 15)];
            int s[16];
            unsigned int v[16];
#pragma unroll
            for (int j = 0; j < 16; j++) s[j] = __shfl(idx16, j, 64);
#pragma unroll
            for (int j = 0; j < 16; j++)
                v[j] = *(const unsigned int*)(Xb + (size_t)s[j] * DIM + lane * 2);
#pragma unroll
            for (int j = 0; j < 16; j++) {
                union { unsigned int u; float f; } lo, hi;
                lo.u = v[j] << 16;
                hi.u = v[j] & 0xffff0000u;
                ax += lo.f;
                ay += hi.f;
            }
        }
        if (base < e) {  // 8-edge tail
            int idx8 = csr[base + (lane & 7)];
            int s[8];
            unsigned int v[8];
#pragma unroll
            for (int j = 0; j < 8; j++) s[j] = __shfl(idx8, j, 64);
#pragma unroll
            for (int j = 0; j < 8; j++)
                v[j] = *(const unsigned int*)(Xb + (size_t)s[j] * DIM + lane * 2);
#pragma unroll
            for (int j = 0; j < 8; j++) {
                union { unsigned int u; float f; } lo, hi;
                lo.u = v[j] << 16;
                hi.u = v[j] & 0xffff0000u;
                ax += lo.f;
                ay += hi.f;
            }
        }
        *(__hip_bfloat162*)(&slds[r * 136 + lane * 2]) =
            __float22bfloat162_rn(make_float2(ax, ay));
    }

    const int rowc = min(row0 + w * 16 + l15, N_NODES);  // pad row is zeros

    f32x4 acc[8];
#pragma unroll
    for (int ct = 0; ct < 8; ct++) acc[ct] = (f32x4){0.f, 0.f, 0.f, 0.f};

    for (int c = 0; c < 2; c++) {
        __syncthreads();  // S-tile ready / protect previous wlds
        {
            int n = tid >> 1, h = tid & 1;
            const uint4* src = (const uint4*)(WT + n * 256 + c * 128 + h * 64);
            uint4* dst = (uint4*)(&wlds[n * 136 + h * 64]);
#pragma unroll
            for (int i = 0; i < 8; i++) dst[i] = src[i];
        }
        __syncthreads();
        const __hip_bfloat16* arow = Xb + (size_t)rowc * DIM;
        const __hip_bfloat16* srow = &slds[(w * 16 + l15) * 136];
#pragma unroll
        for (int ks = 0; ks < 4; ks++) {
            bf16x8 afrag;
            if (c == 0) afrag = *(const bf16x8*)(arow + ks * 32 + q * 8);
            else        afrag = *(const bf16x8*)(srow + ks * 32 + q * 8);
#pragma unroll
            for (int ct = 0; ct < 8; ct++) {
                bf16x8 bfrag = *(const bf16x8*)(&wlds[(ct * 16 + l15) * 136 + ks * 32 + q * 8]);
                acc[ct] = __builtin_amdgcn_mfma_f32_16x16x32_bf16(afrag, bfrag, acc[ct], 0, 0, 0);
            }
        }
    }

    // epilogue: lane holds rows (q*4+r), cols (ct*16+l15)
    const int growbase = row0 + w * 16;
#pragma unroll
    for (int r = 0; r < 4; r++) {
        int grow = growbase + q * 4 + r;
        bool valid = grow < N_NODES;
        float dg = valid ? (float)deg[grow] : 0.f;
        float v[8];
        float s1 = 0.f;
#pragma unroll
        for (int ct = 0; ct < 8; ct++) {
            int col = ct * 16 + l15;
            float h = acc[ct][r] + bself[col] + dg * bmsg[col];
            h = fmaxf(h, 0.f);
            v[ct] = h;
            s1 += h;
        }
        if (do_ln) {
#pragma unroll
            for (int m = 1; m < 16; m <<= 1) s1 += __shfl_xor(s1, m, 64);
            float mu = s1 * (1.0f / 128.0f);
            float s2 = 0.f;
#pragma unroll
            for (int ct = 0; ct < 8; ct++) { float d = v[ct] - mu; s2 += d * d; }
#pragma unroll
            for (int m = 1; m < 16; m <<= 1) s2 += __shfl_xor(s2, m, 64);
            float rs = rsqrtf(s2 * (1.0f / 128.0f) + LN_EPS);
#pragma unroll
            for (int ct = 0; ct < 8; ct++) {
                int col = ct * 16 + l15;
                v[ct] = lng[col] * (v[ct] - mu) * rs + lnb[col];
            }
        }
        if (valid) {
#pragma unroll
            for (int ct = 0; ct < 8; ct++) {
                int col = ct * 16 + l15;
                XoutB[(size_t)grow * DIM + col] = __float2bfloat16(v[ct]);
            }
        }
    }
}

// ---- Global mean pool (partial sums) + head --------------------------------

__global__ __launch_bounds__(128) void pool_partial_kernel(const __hip_bfloat16* __restrict__ X,
                                                           const int* __restrict__ batch,
                                                           float* __restrict__ gsum) {
    int g = blockIdx.x;
    int s = blockIdx.y;
    int lo = lower_bound_i(batch, N_NODES, g);
    int hi = lower_bound_i(batch, N_NODES, g + 1);
    int len = hi - lo;
    int a = lo + (int)(((long long)len * s) / PSPLIT);
    int b = lo + (int)(((long long)len * (s + 1)) / PSPLIT);
    int c = threadIdx.x;
    float acc = 0.f;
    for (int n = a; n < b; n++) acc += __bfloat162float(X[(size_t)n * DIM + c]);
    if (b > a) atomicAdd(&gsum[g * DIM + c], acc);
}

__global__ __launch_bounds__(128) void head_kernel(
    const float* __restrict__ gsum, const int* __restrict__ batch,
    const float* __restrict__ W1, const float* __restrict__ b1,
    const float* __restrict__ W2, const float* __restrict__ b2,
    float* __restrict__ out) {
    __shared__ float p[128];
    __shared__ float hh[128];
    int g = blockIdx.x;
    int j = threadIdx.x;
    int lo = lower_bound_i(batch, N_NODES, g);
    int hi = lower_bound_i(batch, N_NODES, g + 1);
    float cnt = fmaxf((float)(hi - lo), 1.0f);
    p[j] = gsum[g * DIM + j] / cnt;
    __syncthreads();
    float s = b1[j];
    for (int k = 0; k < DIM; k++) s += p[k] * W1[k * DIM + j];
    hh[j] = s;
    __syncthreads();
    if (j < CLS) {
        float l = b2[j];
        for (int k = 0; k < DIM; k++) l += hh[k] * W2[k * CLS + j];
        float mx = l;
#pragma unroll
        for (int m = 16; m >= 1; m >>= 1) mx = fmaxf(mx, __shfl_xor(mx, m, 64));
        float ex = expf(l - mx);
        float se = ex;
#pragma unroll
        for (int m = 16; m >= 1; m >>= 1) se += __shfl_xor(se, m, 64);
        out[g * CLS + j] = l - mx - logf(se);
    }
}

// ---- launch ----------------------------------------------------------------

extern "C" void kernel_launch(void* const* d_in, const int* in_sizes, int n_in,
                              void* d_out, int out_size, void* d_ws, size_t ws_size,
                              hipStream_t stream) {
    (void)in_sizes; (void)n_in; (void)out_size; (void)ws_size;
    const float* x     = (const float*)d_in[0];
    const float* Wself = (const float*)d_in[1];
    const float* bself = (const float*)d_in[2];
    const float* Wmsg  = (const float*)d_in[3];
    const float* bmsg  = (const float*)d_in[4];
    const float* lng   = (const float*)d_in[5];
    const float* lnb   = (const float*)d_in[6];
    const float* W1    = (const float*)d_in[7];
    const float* b1    = (const float*)d_in[8];
    const float* W2    = (const float*)d_in[9];
    const float* b2    = (const float*)d_in[10];
    const int*   ei    = (const int*)d_in[11];
    const int*   batch = (const int*)d_in[12];
    const int* esrc = ei;
    const int* edst = ei + N_EDGES;

    char* w = (char*)d_ws;
    size_t o = 0;
    auto alloc = [&](size_t bytes) { void* p = w + o; o += (bytes + 255) & ~(size_t)255; return p; };
    __hip_bfloat16* XbIn = (__hip_bfloat16*)alloc((size_t)ROWS1 * DIM * 2);
    __hip_bfloat16* Xb0  = (__hip_bfloat16*)alloc((size_t)ROWS1 * DIM * 2);
    __hip_bfloat16* Xb1  = (__hip_bfloat16*)alloc((size_t)ROWS1 * DIM * 2);
    __hip_bfloat16* WT   = (__hip_bfloat16*)alloc((size_t)3 * 128 * 256 * 2);
    int*   counts = (int*)alloc((size_t)N_NODES * 4);
    int*   offs   = (int*)alloc((size_t)(N_NODES + 1) * 4);
    int*   btot   = (int*)alloc((size_t)NBLK * 4);
    int*   bbase  = (int*)alloc((size_t)NBLK * 4);
    int*   ecur   = (int*)alloc((size_t)NBLK * 4);
    int*   ebuf   = (int*)alloc((size_t)NBLK * EB_STRIDE * 4);
    int*   csr    = (int*)alloc((size_t)CSR_CAP * 4);
    float* gsum   = (float*)alloc((size_t)NGRAPH * DIM * 4);

    // fused prep: bf16 convert + WT transpose + zero ecur/gsum/pad rows
    prep_kernel<<<(N_NODES * DIM / 2 + 255) / 256, 256, 0, stream>>>(
        x, Wself, Wmsg, XbIn, WT, ecur, gsum,
        XbIn + (size_t)N_NODES * DIM, Xb0 + (size_t)N_NODES * DIM,
        Xb1 + (size_t)N_NODES * DIM);

    // CSR build: bucket -> per-bucket hist -> bucket scan -> LDS-local build
    bucket_kernel<<<ABLK, 1024, 0, stream>>>(esrc, edst, ecur, ebuf);
    bhist_kernel<<<NBLK, 1024, 0, stream>>>(ebuf, ecur, counts, btot);
    btot_scan_kernel<<<1, 256, 0, stream>>>(btot, bbase, offs);
    csr_build_kernel<<<NBLK, 1024, 0, stream>>>(ebuf, ecur, counts, bbase, offs, csr);

    const __hip_bfloat16* XbCur = XbIn;
    __hip_bfloat16* bbufs[3] = {Xb0, Xb1, Xb0};
    for (int i = 0; i < 3; i++) {
        layer_fused_kernel<<<(N_NODES + 63) / 64, 256, 0, stream>>>(
            XbCur, offs, csr, WT + (size_t)i * 128 * 256,
            bself + i * DIM, bmsg + i * DIM, counts,
            (i < 2) ? lng + i * DIM : lng, (i < 2) ? lnb + i * DIM : lnb,
            bbufs[i], (i < 2) ? 1 : 0);
        XbCur = bbufs[i];
    }

    pool_partial_kernel<<<dim3(NGRAPH, PSPLIT), 128, 0, stream>>>(bbufs[2], batch, gsum);
    head_kernel<<<NGRAPH, 128, 0, stream>>>(gsum, batch, W1, b1, W2, b2, (float*)d_out);
}

// Round 13
// 294.335 us; speedup vs baseline: 1.2317x; 1.2317x over previous
//
#include <hip/hip_runtime.h>
#include <hip/hip_bf16.h>
#include <math.h>

#define N_NODES 50000
#define N_EDGES 800000
#define DIM 128
#define CLS 32
#define NGRAPH 64
#define LN_EPS 1e-5f
// padded CSR capacity: sum ceil(deg/8)*8 <= E + 7*N
#define CSR_CAP (N_EDGES + 8 * N_NODES)
#define NBLK 196                         // dst-buckets of 256 nodes
#define ABLK 128                         // phase-A blocks
#define EPB (N_EDGES / ABLK)             // 6250 edges per phase-A block
#define EB_STRIDE 7168                   // per-bucket ebuf capacity
#define LCAP 8192                        // per-bucket LDS csr capacity
#define PSPLIT 16                        // pool partial splits per graph
#define ROWS1 (N_NODES + 1)              // 50001 (incl zero pad row)

typedef __attribute__((ext_vector_type(8))) short bf16x8;
typedef __attribute__((ext_vector_type(4))) float f32x4;

static __device__ __forceinline__ int lower_bound_i(const int* a, int n, int key) {
    int lo = 0, hi = n;
    while (lo < hi) { int mid = (lo + hi) >> 1; if (a[mid] < key) lo = mid + 1; else hi = mid; }
    return lo;
}

// ---- fused prep: row-major bf16 convert + weight transpose + zero scratch --

__global__ __launch_bounds__(256) void prep_kernel(
    const float* __restrict__ x, const float* __restrict__ Wself,
    const float* __restrict__ Wmsg, __hip_bfloat16* __restrict__ XbIn,
    __hip_bfloat16* __restrict__ WT,
    int* __restrict__ ecur, float* __restrict__ gsum,
    __hip_bfloat16* __restrict__ padA, __hip_bfloat16* __restrict__ padB,
    __hip_bfloat16* __restrict__ padC) {
    int i = blockIdx.x * 256 + threadIdx.x;  // grid covers N_NODES*DIM/2 = 3.2M
    if (i < N_NODES * DIM / 2) {
        float2 v = ((const float2*)x)[i];
        ((__hip_bfloat162*)XbIn)[i] = __float22bfloat162_rn(v);
    }
    if (i < 3 * 128 * 256) {
        int l = i / (128 * 256);
        int rem = i - l * (128 * 256);
        int n = rem >> 8;
        int k = rem & 255;
        float v = (k < 128) ? Wself[l * 16384 + k * 128 + n]
                            : Wmsg[l * 16384 + (k - 128) * 128 + n];
        WT[i] = __float2bfloat16(v);
    }
    if (i < NBLK) ecur[i] = i * EB_STRIDE;
    if (i < NGRAPH * DIM) gsum[i] = 0.f;
    if (i < DIM) {  // zero pad row (n = N_NODES) of the bf16 node buffers
        padA[i] = __float2bfloat16(0.f);
        padB[i] = __float2bfloat16(0.f);
        padC[i] = __float2bfloat16(0.f);
    }
}

// ---- phase A: bucket edges by dst>>8, line-exclusive reservations ----------

__global__ __launch_bounds__(1024) void bucket_kernel(
    const int* __restrict__ esrc, const int* __restrict__ edst,
    int* __restrict__ ecur, int* __restrict__ ebuf) {
    __shared__ int bc[NBLK], bres[NBLK], bcnt[NBLK];
    const int t = threadIdx.x;
    const int e0 = blockIdx.x * EPB;
    if (t < NBLK) bc[t] = 0;
    __syncthreads();
    for (int i = t; i < EPB; i += 1024)
        atomicAdd(&bc[edst[e0 + i] >> 8], 1);
    __syncthreads();
    if (t < NBLK) {
        int c = bc[t];
        int r = (c + 15) & ~15;                 // whole 64B lines
        int res = atomicAdd(&ecur[t], r);       // one global atomic per (block,bucket)
        bres[t] = res;
        bcnt[t] = c;
        bc[t] = res;
    }
    __syncthreads();
    for (int i = t; i < EPB; i += 1024) {
        int d = edst[e0 + i];
        int s = esrc[e0 + i];
        int pos = atomicAdd(&bc[d >> 8], 1);
        ebuf[pos] = ((d & 255) << 16) | s;      // src < 50000 < 2^16
    }
    __syncthreads();
    if (t < NBLK) {
        int c = bcnt[t], r = (c + 15) & ~15, base = bres[t];
        for (int j = c; j < r; j++) ebuf[base + j] = -1;  // sentinels
    }
}

// ---- phase B1: per-bucket node histogram from ebuf -------------------------

__global__ __launch_bounds__(1024) void bhist_kernel(
    const int* __restrict__ ebuf, const int* __restrict__ ecur,
    int* __restrict__ counts, int* __restrict__ btot) {
    __shared__ int ncnt[256];
    __shared__ int red[256];
    const int b = blockIdx.x, t = threadIdx.x;
    const int used = ecur[b] - b * EB_STRIDE;
    const int* eb = ebuf + b * EB_STRIDE;
    if (t < 256) ncnt[t] = 0;
    __syncthreads();
    for (int i = t; i < used; i += 1024) {
        int p = eb[i];
        if (p != -1) atomicAdd(&ncnt[p >> 16], 1);
    }
    __syncthreads();
    if (t < 256) {
        int gi = b * 256 + t;
        if (gi < N_NODES) counts[gi] = ncnt[t];
        red[t] = (ncnt[t] + 7) & ~7;
    }
    __syncthreads();
    for (int o = 128; o > 0; o >>= 1) {
        if (t < o) red[t] += red[t + o];
        __syncthreads();
    }
    if (t == 0) btot[b] = red[0];
}

// ---- phase B2: exclusive scan of 196 padded bucket totals ------------------

__global__ __launch_bounds__(256) void btot_scan_kernel(const int* __restrict__ btot,
                                                        int* __restrict__ bbase,
                                                        int* __restrict__ off) {
    __shared__ int sd[256];
    int i = threadIdx.x;
    int v = (i < NBLK) ? btot[i] : 0;
    sd[i] = v;
    __syncthreads();
    for (int o = 1; o < 256; o <<= 1) {
        int tv = (i >= o) ? sd[i - o] : 0;
        __syncthreads();
        sd[i] += tv;
        __syncthreads();
    }
    if (i < NBLK) bbase[i] = sd[i] - v;  // exclusive
    if (i == 255) off[N_NODES] = sd[255];
}

// ---- phase B3: per-bucket CSR build in LDS; writes off[] + coalesced csr ---

__global__ __launch_bounds__(1024) void csr_build_kernel(
    const int* __restrict__ ebuf, const int* __restrict__ ecur,
    const int* __restrict__ counts, const int* __restrict__ bbase,
    int* __restrict__ off, int* __restrict__ csr) {
    __shared__ int cur[256];
    __shared__ int ssc[256];
    __shared__ int lcsr[LCAP];
    const int b = blockIdx.x, t = threadIdx.x;
    const int used = ecur[b] - b * EB_STRIDE;
    const int* eb = ebuf + b * EB_STRIDE;
    const int gbase = bbase[b];
    for (int i = t; i < LCAP; i += 1024) lcsr[i] = N_NODES;  // pads -> zero row
    int myc = 0, mypad = 0;
    const int gi = b * 256 + t;
    if (t < 256) {
        myc = (gi < N_NODES) ? counts[gi] : 0;
        mypad = (myc + 7) & ~7;
        ssc[t] = mypad;
    }
    __syncthreads();
    for (int o = 1; o < 256; o <<= 1) {
        int v = 0;
        if (t < 256 && t >= o) v = ssc[t - o];
        __syncthreads();
        if (t < 256) ssc[t] += v;
        __syncthreads();
    }
    if (t < 256) {
        int eoff = ssc[t] - mypad;
        cur[t] = eoff;
        if (gi < N_NODES) off[gi] = gbase + eoff;
    }
    __syncthreads();
    for (int i = t; i < used; i += 1024) {
        int p = eb[i];
        if (p != -1) {
            int pos = atomicAdd(&cur[p >> 16], 1);
            lcsr[pos] = p & 0xFFFF;
        }
    }
    __syncthreads();
    const int total = ssc[255];
    int4* dst4 = (int4*)(csr + gbase);
    const int4* src4 = (const int4*)lcsr;
    for (int i = t; i < (total >> 2); i += 1024) dst4[i] = src4[i];
}

// ---- Neighbor sum: Sb[n,:] = sum_{e in CSR[n]} Xb[src[e],:] (bf16 in/out) --
// One wave per node. uint4 gather: 16 lanes cover one 256 B row (16 B/lane),
// 4 edges per round, 4 rounds per 16-edge chunk -> 4 VMEM + 4 shfl per chunk
// (vs 16+16 scalar). Same 64 B/lane outstanding. Cross-group reduce at end.

__global__ __launch_bounds__(256) void agg_kernel(const __hip_bfloat16* __restrict__ Xb,
                                                  const int* __restrict__ off,
                                                  const int* __restrict__ csr,
                                                  __hip_bfloat16* __restrict__ Sb) {
    const int wave = threadIdx.x >> 6;
    const int lane = threadIdx.x & 63;
    const int n = blockIdx.x * 4 + wave;
    if (n >= N_NODES) return;
    const int seg = lane >> 4;   // edge-within-round 0..3
    const int cl = lane & 15;    // 16 B segment within the 256 B row
    int b = off[n], e = off[n + 1];  // padded: (e-b) % 8 == 0
    float ac[8];
#pragma unroll
    for (int j = 0; j < 8; j++) ac[j] = 0.f;
    int base = b;
    for (; base + 16 <= e; base += 16) {
        int idx16 = csr[base + (lane & 15)];
        int s[4];
        uint4 v[4];
#pragma unroll
        for (int r = 0; r < 4; r++) s[r] = __shfl(idx16, r * 4 + seg, 64);
#pragma unroll
        for (int r = 0; r < 4; r++)
            v[r] = *(const uint4*)(Xb + (size_t)s[r] * DIM + cl * 8);
#pragma unroll
        for (int r = 0; r < 4; r++) {
            unsigned int u[4] = {v[r].x, v[r].y, v[r].z, v[r].w};
#pragma unroll
            for (int k = 0; k < 4; k++) {
                union { unsigned int b32; float f; } lo, hi;
                lo.b32 = u[k] << 16;
                hi.b32 = u[k] & 0xffff0000u;
                ac[2 * k] += lo.f;
                ac[2 * k + 1] += hi.f;
            }
        }
    }
    if (base < e) {  // 8-edge tail: 2 rounds
        int idx8 = csr[base + (lane & 7)];
        int s0 = __shfl(idx8, seg, 64);
        int s1 = __shfl(idx8, 4 + seg, 64);
        uint4 v0 = *(const uint4*)(Xb + (size_t)s0 * DIM + cl * 8);
        uint4 v1 = *(const uint4*)(Xb + (size_t)s1 * DIM + cl * 8);
        unsigned int u[8] = {v0.x, v0.y, v0.z, v0.w, v1.x, v1.y, v1.z, v1.w};
#pragma unroll
        for (int k = 0; k < 8; k++) {
            union { unsigned int b32; float f; } lo, hi;
            lo.b32 = u[k] << 16;
            hi.b32 = u[k] & 0xffff0000u;
            ac[2 * (k & 3)] += lo.f;
            ac[2 * (k & 3) + 1] += hi.f;
        }
    }
    // reduce across the 4 lane-groups (lane bits 4,5)
#pragma unroll
    for (int j = 0; j < 8; j++) {
        ac[j] += __shfl_xor(ac[j], 16, 64);
        ac[j] += __shfl_xor(ac[j], 32, 64);
    }
    if (lane < 16) {
        union { uint4 u; __hip_bfloat162 h[4]; } pk;
#pragma unroll
        for (int k = 0; k < 4; k++)
            pk.h[k] = __float22bfloat162_rn(make_float2(ac[2 * k], ac[2 * k + 1]));
        *(uint4*)(Sb + (size_t)n * DIM + cl * 8) = pk.u;
    }
}

// ---- Fused layer via MFMA: H = [Xb|Sb] @ WT^T; +bias+deg*bmsg, ReLU, LN ----

__global__ __launch_bounds__(256) void layer_mfma_kernel(
    const __hip_bfloat16* __restrict__ Xb, const __hip_bfloat16* __restrict__ Sb,
    const __hip_bfloat16* __restrict__ WT,  // [128 n][256 k] bf16 for this layer
    const float* __restrict__ bself, const float* __restrict__ bmsg,
    const int* __restrict__ deg,
    const float* __restrict__ lng, const float* __restrict__ lnb,
    __hip_bfloat16* __restrict__ XoutB, int do_ln) {
    // stride 136 bf16 = 272 B (16B-aligned rows, 2-way bank aliasing = free)
    __shared__ __hip_bfloat16 wlds[128 * 136];
    const int tid = threadIdx.x;
    const int w = tid >> 6, lane = tid & 63;
    const int l15 = lane & 15, q = lane >> 4;

    const int row = blockIdx.x * 64 + w * 16 + l15;
    const int rowc = min(row, N_NODES);  // pad row N_NODES is all zeros

    f32x4 acc[8];
#pragma unroll
    for (int ct = 0; ct < 8; ct++) acc[ct] = (f32x4){0.f, 0.f, 0.f, 0.f};

    const __hip_bfloat16* Abase[2] = {Xb, Sb};
    for (int c = 0; c < 2; c++) {
        __syncthreads();
        {
            int n = tid >> 1, h = tid & 1;
            const uint4* src = (const uint4*)(WT + n * 256 + c * 128 + h * 64);
            uint4* dst = (uint4*)(&wlds[n * 136 + h * 64]);
#pragma unroll
            for (int i = 0; i < 8; i++) dst[i] = src[i];
        }
        __syncthreads();
        const __hip_bfloat16* arow = Abase[c] + (size_t)rowc * DIM;
#pragma unroll
        for (int ks = 0; ks < 4; ks++) {
            bf16x8 afrag = *(const bf16x8*)(arow + ks * 32 + q * 8);
#pragma unroll
            for (int ct = 0; ct < 8; ct++) {
                bf16x8 bfrag = *(const bf16x8*)(&wlds[(ct * 16 + l15) * 136 + ks * 32 + q * 8]);
                acc[ct] = __builtin_amdgcn_mfma_f32_16x16x32_bf16(afrag, bfrag, acc[ct], 0, 0, 0);
            }
        }
    }

    // epilogue: lane holds rows (q*4+r), cols (ct*16+l15)
    const int growbase = blockIdx.x * 64 + w * 16;
#pragma unroll
    for (int r = 0; r < 4; r++) {
        int grow = growbase + q * 4 + r;
        bool valid = grow < N_NODES;
        float dg = valid ? (float)deg[grow] : 0.f;
        float v[8];
        float s1 = 0.f;
#pragma unroll
        for (int ct = 0; ct < 8; ct++) {
            int col = ct * 16 + l15;
            float h = acc[ct][r] + bself[col] + dg * bmsg[col];
            h = fmaxf(h, 0.f);
            v[ct] = h;
            s1 += h;
        }
        if (do_ln) {
#pragma unroll
            for (int m = 1; m < 16; m <<= 1) s1 += __shfl_xor(s1, m, 64);
            float mu = s1 * (1.0f / 128.0f);
            float s2 = 0.f;
#pragma unroll
            for (int ct = 0; ct < 8; ct++) { float d = v[ct] - mu; s2 += d * d; }
#pragma unroll
            for (int m = 1; m < 16; m <<= 1) s2 += __shfl_xor(s2, m, 64);
            float rs = rsqrtf(s2 * (1.0f / 128.0f) + LN_EPS);
#pragma unroll
            for (int ct = 0; ct < 8; ct++) {
                int col = ct * 16 + l15;
                v[ct] = lng[col] * (v[ct] - mu) * rs + lnb[col];
            }
        }
        if (valid) {
#pragma unroll
            for (int ct = 0; ct < 8; ct++) {
                int col = ct * 16 + l15;
                XoutB[(size_t)grow * DIM + col] = __float2bfloat16(v[ct]);
            }
        }
    }
}

// ---- Global mean pool (partial sums) + head --------------------------------

__global__ __launch_bounds__(128) void pool_partial_kernel(const __hip_bfloat16* __restrict__ X,
                                                           const int* __restrict__ batch,
                                                           float* __restrict__ gsum) {
    int g = blockIdx.x;
    int s = blockIdx.y;
    int lo = lower_bound_i(batch, N_NODES, g);
    int hi = lower_bound_i(batch, N_NODES, g + 1);
    int len = hi - lo;
    int a = lo + (int)(((long long)len * s) / PSPLIT);
    int b = lo + (int)(((long long)len * (s + 1)) / PSPLIT);
    int c = threadIdx.x;
    float acc = 0.f;
    for (int n = a; n < b; n++) acc += __bfloat162float(X[(size_t)n * DIM + c]);
    if (b > a) atomicAdd(&gsum[g * DIM + c], acc);
}

__global__ __launch_bounds__(128) void head_kernel(
    const float* __restrict__ gsum, const int* __restrict__ batch,
    const float* __restrict__ W1, const float* __restrict__ b1,
    const float* __restrict__ W2, const float* __restrict__ b2,
    float* __restrict__ out) {
    __shared__ float p[128];
    __shared__ float hh[128];
    int g = blockIdx.x;
    int j = threadIdx.x;
    int lo = lower_bound_i(batch, N_NODES, g);
    int hi = lower_bound_i(batch, N_NODES, g + 1);
    float cnt = fmaxf((float)(hi - lo), 1.0f);
    p[j] = gsum[g * DIM + j] / cnt;
    __syncthreads();
    float s = b1[j];
    for (int k = 0; k < DIM; k++) s += p[k] * W1[k * DIM + j];
    hh[j] = s;
    __syncthreads();
    if (j < CLS) {
        float l = b2[j];
        for (int k = 0; k < DIM; k++) l += hh[k] * W2[k * CLS + j];
        float mx = l;
#pragma unroll
        for (int m = 16; m >= 1; m >>= 1) mx = fmaxf(mx, __shfl_xor(mx, m, 64));
        float ex = expf(l - mx);
        float se = ex;
#pragma unroll
        for (int m = 16; m >= 1; m >>= 1) se += __shfl_xor(se, m, 64);
        out[g * CLS + j] = l - mx - logf(se);
    }
}

// ---- launch ----------------------------------------------------------------

extern "C" void kernel_launch(void* const* d_in, const int* in_sizes, int n_in,
                              void* d_out, int out_size, void* d_ws, size_t ws_size,
                              hipStream_t stream) {
    (void)in_sizes; (void)n_in; (void)out_size; (void)ws_size;
    const float* x     = (const float*)d_in[0];
    const float* Wself = (const float*)d_in[1];
    const float* bself = (const float*)d_in[2];
    const float* Wmsg  = (const float*)d_in[3];
    const float* bmsg  = (const float*)d_in[4];
    const float* lng   = (const float*)d_in[5];
    const float* lnb   = (const float*)d_in[6];
    const float* W1    = (const float*)d_in[7];
    const float* b1    = (const float*)d_in[8];
    const float* W2    = (const float*)d_in[9];
    const float* b2    = (const float*)d_in[10];
    const int*   ei    = (const int*)d_in[11];
    const int*   batch = (const int*)d_in[12];
    const int* esrc = ei;
    const int* edst = ei + N_EDGES;

    char* w = (char*)d_ws;
    size_t o = 0;
    auto alloc = [&](size_t bytes) { void* p = w + o; o += (bytes + 255) & ~(size_t)255; return p; };
    __hip_bfloat16* XbIn = (__hip_bfloat16*)alloc((size_t)ROWS1 * DIM * 2);
    __hip_bfloat16* Xb0  = (__hip_bfloat16*)alloc((size_t)ROWS1 * DIM * 2);
    __hip_bfloat16* Xb1  = (__hip_bfloat16*)alloc((size_t)ROWS1 * DIM * 2);
    __hip_bfloat16* Sb   = (__hip_bfloat16*)alloc((size_t)ROWS1 * DIM * 2);
    __hip_bfloat16* WT   = (__hip_bfloat16*)alloc((size_t)3 * 128 * 256 * 2);
    int*   counts = (int*)alloc((size_t)N_NODES * 4);
    int*   offs   = (int*)alloc((size_t)(N_NODES + 1) * 4);
    int*   btot   = (int*)alloc((size_t)NBLK * 4);
    int*   bbase  = (int*)alloc((size_t)NBLK * 4);
    int*   ecur   = (int*)alloc((size_t)NBLK * 4);
    int*   ebuf   = (int*)alloc((size_t)NBLK * EB_STRIDE * 4);
    int*   csr    = (int*)alloc((size_t)CSR_CAP * 4);
    float* gsum   = (float*)alloc((size_t)NGRAPH * DIM * 4);

    // fused prep: bf16 convert + WT transpose + zero ecur/gsum/pad rows
    // (Sb pad row is never read: agg writes all rows incl. none of pad; layer
    //  reads Sb only for rowc<=N_NODES, so zero XbIn/Xb0/Xb1 pads + Sb pad via
    //  padC slot -> pass Sb pad too by reusing one slot each launch)
    prep_kernel<<<(N_NODES * DIM / 2 + 255) / 256, 256, 0, stream>>>(
        x, Wself, Wmsg, XbIn, WT, ecur, gsum,
        XbIn + (size_t)N_NODES * DIM, Xb0 + (size_t)N_NODES * DIM,
        Xb1 + (size_t)N_NODES * DIM);
    // zero Sb pad row (read by layer when rowc==N_NODES in phase 1)
    hipMemsetAsync(Sb + (size_t)N_NODES * DIM, 0, DIM * 2, stream);

    // CSR build: bucket -> per-bucket hist -> bucket scan -> LDS-local build
    bucket_kernel<<<ABLK, 1024, 0, stream>>>(esrc, edst, ecur, ebuf);
    bhist_kernel<<<NBLK, 1024, 0, stream>>>(ebuf, ecur, counts, btot);
    btot_scan_kernel<<<1, 256, 0, stream>>>(btot, bbase, offs);
    csr_build_kernel<<<NBLK, 1024, 0, stream>>>(ebuf, ecur, counts, bbase, offs, csr);

    const __hip_bfloat16* XbCur = XbIn;
    __hip_bfloat16* bbufs[3] = {Xb0, Xb1, Xb0};
    for (int i = 0; i < 3; i++) {
        agg_kernel<<<(N_NODES + 3) / 4, 256, 0, stream>>>(XbCur, offs, csr, Sb);
        layer_mfma_kernel<<<(N_NODES + 63) / 64, 256, 0, stream>>>(
            XbCur, Sb, WT + (size_t)i * 128 * 256,
            bself + i * DIM, bmsg + i * DIM, counts,
            (i < 2) ? lng + i * DIM : lng, (i < 2) ? lnb + i * DIM : lnb,
            bbufs[i], (i < 2) ? 1 : 0);
        XbCur = bbufs[i];
    }

    pool_partial_kernel<<<dim3(NGRAPH, PSPLIT), 128, 0, stream>>>(bbufs[2], batch, gsum);
    head_kernel<<<NGRAPH, 128, 0, stream>>>(gsum, batch, W1, b1, W2, b2, (float*)d_out);
}